// Round 6
// baseline (168.986 us; speedup 1.0000x reference)
//
#include <hip/hip_runtime.h>
#include <hip/hip_bf16.h>

#define BATCH 8
#define TDIM  2048
#define CDIM  1024
#define DDIM  128

typedef float  f32x4  __attribute__((ext_vector_type(4)));
typedef __bf16 bf16x8 __attribute__((ext_vector_type(8)));
typedef unsigned short u16;
typedef unsigned int   u32;
typedef u16 u16x4 __attribute__((ext_vector_type(4)));
typedef u16 u16x8 __attribute__((ext_vector_type(8)));
typedef u32 u32x4 __attribute__((ext_vector_type(4)));

static __device__ __forceinline__ u16 f2bf(float f) {
    union { float f; unsigned int u; } cv;
    cv.f = f;
    unsigned int lsb = (cv.u >> 16) & 1u;
    cv.u += 0x7fffu + lsb;          // round-to-nearest-even
    return (u16)(cv.u >> 16);
}

static __device__ __forceinline__ float bf2f(u16 v) {
    union { u32 u; float f; } cv;
    cv.u = (u32)v << 16;
    return cv.f;
}

static __device__ __forceinline__ u32 packbf(float a, float b) {
    return (u32)f2bf(a) | ((u32)f2bf(b) << 16);
}

static __device__ __forceinline__ void gload16(const u16* g, u16* l) {
    __builtin_amdgcn_global_load_lds(
        (const __attribute__((address_space(1))) void*)g,
        (__attribute__((address_space(3))) void*)l, 16, 0, 0);
}

#define SCHED_FENCE() __builtin_amdgcn_sched_barrier(0)
#define BARRIER()     __builtin_amdgcn_s_barrier()

// ---------------------------------------------------------------------------
// Kernel 0: W fp32 -> tiled bf16.  wb[which][kb:16][kk2:2][cb:4][row:128][8]
// (k = kb*64 + kk2*32 + cb*8 + e).  48 blocks, tiny.
// ---------------------------------------------------------------------------
__global__ __launch_bounds__(256) void convert_w(
    const float* __restrict__ Wq, const float* __restrict__ Wk,
    const float* __restrict__ Wv, u16* __restrict__ wb)
{
    const int which = blockIdx.x >> 4;
    const int kb    = blockIdx.x & 15;
    const float* W = (which == 0) ? Wq : (which == 1) ? Wk : Wv;
    u16* dst = wb + ((size_t)(which * 16 + kb)) * 8192;
    const int t = threadIdx.x;
    for (int i = 0; i < 4; ++i) {
        int j   = i * 256 + t;              // 0..1023 = kk2*512 + cb*128 + row
        int row = j & 127;
        int cb  = (j >> 7) & 3;
        int kk2 = j >> 9;
        const float* s = &W[(size_t)row * CDIM + kb * 64 + kk2 * 32 + cb * 8];
        f32x4 a = *reinterpret_cast<const f32x4*>(s);
        f32x4 b = *reinterpret_cast<const f32x4*>(s + 4);
        u16x8 o;
        o[0] = f2bf(a[0]); o[1] = f2bf(a[1]); o[2] = f2bf(a[2]); o[3] = f2bf(a[3]);
        o[4] = f2bf(b[0]); o[5] = f2bf(b[1]); o[6] = f2bf(b[2]); o[7] = f2bf(b[3]);
        *reinterpret_cast<u16x8*>(dst + (size_t)j * 8) = o;
    }
}

// ---------------------------------------------------------------------------
// Kernel 1: fused QKV GEMM, software-pipelined (dbuf LDS, counted vmcnt,
// raw s_barrier — one barrier per K-step, staging hidden under MFMA).
// 64x128 tile, BK=64, 4 waves.  Grid 768 = 3 x 256 row-tiles (3 blocks/CU).
// A (x fp32) reg-staged 2 ahead + converted to bf16; B gload_lds 1 ahead.
// ---------------------------------------------------------------------------
__global__ __launch_bounds__(256) void qkv_gemm(
    const float* __restrict__ x, const u16* __restrict__ wb,
    u16* __restrict__ Qw, u16* __restrict__ Ktl, u16* __restrict__ Vtl)
{
    __shared__ alignas(16) u16 As[2][4096];    // 8KB each  [kk2:2][cb:4][row:64][8]
    __shared__ alignas(16) u16 Bs[2][8192];    // 16KB each [kk2:2][cb:4][row:128][8]

    const int bid   = blockIdx.x;
    const int which = bid >> 8;             // 0=Q 1=K 2=V
    const int mt    = bid & 255;            // 64-row tile
    const int rbase = mt * 64;
    const u16* Bb = wb + (size_t)which * 131072;

    const int tid  = threadIdx.x;
    const int wid  = tid >> 6;
    const int lane = tid & 63;
    const int g    = lane >> 4;
    const int lr   = lane & 15;
    const int wc   = wid * 32;

    const int arow = tid >> 2;              // 0..63
    const int aseg = tid & 3;               // 16 k-values each
    const int abase = (aseg >> 1) * 2048 + (aseg & 1) * 1024 + arow * 8;
    const float* xrow = &x[(size_t)(rbase + arow) * CDIM + aseg * 16];

    f32x4 ar[4], an[4];
    #define LOADA(dst, kb_) { \
        const float* ax_ = xrow + (kb_) * 64; \
        dst[0] = *reinterpret_cast<const f32x4*>(ax_); \
        dst[1] = *reinterpret_cast<const f32x4*>(ax_ + 4); \
        dst[2] = *reinterpret_cast<const f32x4*>(ax_ + 8); \
        dst[3] = *reinterpret_cast<const f32x4*>(ax_ + 12); }
    #define CONVA(src, buf_) { \
        u16x8 p0_, p1_; \
        p0_[0]=f2bf(src[0][0]); p0_[1]=f2bf(src[0][1]); p0_[2]=f2bf(src[0][2]); p0_[3]=f2bf(src[0][3]); \
        p0_[4]=f2bf(src[1][0]); p0_[5]=f2bf(src[1][1]); p0_[6]=f2bf(src[1][2]); p0_[7]=f2bf(src[1][3]); \
        p1_[0]=f2bf(src[2][0]); p1_[1]=f2bf(src[2][1]); p1_[2]=f2bf(src[2][2]); p1_[3]=f2bf(src[2][3]); \
        p1_[4]=f2bf(src[3][0]); p1_[5]=f2bf(src[3][1]); p1_[6]=f2bf(src[3][2]); p1_[7]=f2bf(src[3][3]); \
        *reinterpret_cast<u16x8*>(&As[buf_][abase])       = p0_; \
        *reinterpret_cast<u16x8*>(&As[buf_][abase + 512]) = p1_; }
    #define LOADB(buf_, kb_) { \
        const u16* Bt_ = Bb + (size_t)(kb_) * 8192; \
        for (int i_ = 0; i_ < 4; ++i_) \
            gload16(Bt_ + (size_t)(i_ * 256 + tid) * 8, &Bs[buf_][(i_ * 256 + wid * 64) * 8]); }

    f32x4 acc[4][2] = {};

    // prologue
    LOADA(ar, 0);
    LOADB(0, 0);
    LOADA(an, 1);
    CONVA(ar, 0);
    asm volatile("s_waitcnt vmcnt(4) lgkmcnt(0)" ::: "memory");  // B0 done, A1 in flight
    SCHED_FENCE(); BARRIER(); SCHED_FENCE();

    for (int kb = 0; kb < 16; ++kb) {
        const int cur = kb & 1, nxt = cur ^ 1;
        if (kb < 15) {
            LOADB(nxt, kb + 1);
            CONVA(an, nxt);                 // auto-waits A(kb+1) regs
            if (kb < 14) LOADA(an, kb + 2);
        }
        // compute on As[cur]/Bs[cur]
        bf16x8 af[2][4], bfr[2][2];
        for (int kk2 = 0; kk2 < 2; ++kk2) {
            for (int mi = 0; mi < 4; ++mi)
                af[kk2][mi] = __builtin_bit_cast(bf16x8, *reinterpret_cast<const u16x8*>(
                    &As[cur][kk2 * 2048 + g * 512 + (mi * 16 + lr) * 8]));
            for (int ni = 0; ni < 2; ++ni)
                bfr[kk2][ni] = __builtin_bit_cast(bf16x8, *reinterpret_cast<const u16x8*>(
                    &Bs[cur][kk2 * 4096 + g * 1024 + (wc + ni * 16 + lr) * 8]));
        }
        for (int kk2 = 0; kk2 < 2; ++kk2)
            for (int mi = 0; mi < 4; ++mi)
                for (int ni = 0; ni < 2; ++ni)
                    acc[mi][ni] = __builtin_amdgcn_mfma_f32_16x16x32_bf16(
                        af[kk2][mi], bfr[kk2][ni], acc[mi][ni], 0, 0, 0);
        if (kb < 14) {
            asm volatile("s_waitcnt vmcnt(4) lgkmcnt(0)" ::: "memory");  // B(kb+1) done
            SCHED_FENCE(); BARRIER(); SCHED_FENCE();
        } else if (kb == 14) {
            asm volatile("s_waitcnt vmcnt(0) lgkmcnt(0)" ::: "memory");
            SCHED_FENCE(); BARRIER(); SCHED_FENCE();
        }
    }

    // --- epilogue: bounce through Bs[0] (16KB), then linear 16B writes ---
    u16* bnc = &Bs[0][0];
    const int b  = mt >> 5;
    const int kt = mt & 31;
    if (which == 0) {
        const float sc = 0.08838834764831845f;   // 1/sqrt(128)
        for (int mi = 0; mi < 4; ++mi)
            for (int ni = 0; ni < 2; ++ni) {
                int row = mi * 16 + g * 4;
                int col = wc + ni * 16 + lr;
                for (int r = 0; r < 4; ++r)
                    bnc[(row + r) * 128 + col] = f2bf(acc[mi][ni][r] * sc);
            }
        __syncthreads();
        u16* dst = Qw + (size_t)rbase * DDIM;
        for (int i = 0; i < 4; ++i)
            *reinterpret_cast<u16x8*>(&dst[(size_t)(i * 256 + tid) * 8]) =
                *reinterpret_cast<const u16x8*>(&bnc[(i * 256 + tid) * 8]);
    } else if (which == 1) {
        for (int mi = 0; mi < 4; ++mi)
            for (int ni = 0; ni < 2; ++ni) {
                int row = mi * 16 + g * 4;
                int col = wc + ni * 16 + lr;               // d
                int ebase = (col >> 5) * 2048 + ((col >> 3) & 3) * 512 + (col & 7);
                for (int r = 0; r < 4; ++r)
                    bnc[ebase + (row + r) * 8] = f2bf(acc[mi][ni][r]);
            }
        __syncthreads();
        u16* dst = Ktl + ((size_t)(b * 32 + kt)) * 8192;
        for (int i = 0; i < 4; ++i)
            *reinterpret_cast<u16x8*>(&dst[(size_t)(i * 256 + tid) * 8]) =
                *reinterpret_cast<const u16x8*>(&bnc[(i * 256 + tid) * 8]);
    } else {
        for (int mi = 0; mi < 4; ++mi)
            for (int ni = 0; ni < 2; ++ni) {
                int row = mi * 16 + g * 4;                 // t_loc base
                int col = wc + ni * 16 + lr;               // d
                for (int r = 0; r < 4; ++r) {
                    int t_loc = row + r;
                    bnc[(t_loc >> 5) * 4096 + ((t_loc >> 3) & 3) * 1024 +
                        col * 8 + (t_loc & 7)] = f2bf(acc[mi][ni][r]);
                }
            }
        __syncthreads();
        u16* dst = Vtl + ((size_t)(b * 32 + kt)) * 8192;
        for (int i = 0; i < 4; ++i)
            *reinterpret_cast<u16x8*>(&dst[(size_t)(i * 256 + tid) * 8]) =
                *reinterpret_cast<const u16x8*>(&bnc[(i * 256 + tid) * 8]);
    }
}

// ---------------------------------------------------------------------------
// Kernel 2: causal flash attention, split-KV span 4, K+V double-buffered in
// LDS (prefetch next tile before compute, drain after -> latency hidden).
// Grid (144, 8).  4 waves x 16 q-rows.  Swapped QK^T, per-lane softmax,
// defer-max (skip O-rescale when max growth <= 8).
// ---------------------------------------------------------------------------
__global__ __launch_bounds__(256) void attn(
    const u16* __restrict__ Qw, const u16* __restrict__ Ktl,
    const u16* __restrict__ Vtl, float* __restrict__ out,
    u16* __restrict__ po, float* __restrict__ pm, float* __restrict__ pl)
{
    __shared__ alignas(16) u16 Ks[2][8192];  // [kk:4][cb:4][row:64][8]
    __shared__ alignas(16) u16 Vs[2][8192];  // [c:2][gk:4][d:128][8]
    constexpr int LDPW = 36;
    __shared__ u32 Plw[4][16 * LDPW];

    const int s = blockIdx.x;
    const int b = blockIdx.y;
    int gg = 0;
    while (s >= 2 * (gg + 1) * (gg + 2)) ++gg;       // group: qt in [4gg, 4gg+4)
    const int r_     = s - 2 * gg * (gg + 1);
    const int qt     = 4 * gg + r_ / (gg + 1);
    const int split  = r_ % (gg + 1);
    const int kt0 = split * 4;
    const int kt1 = min(kt0 + 4, qt + 1);

    const int tid  = threadIdx.x;
    const int wid  = tid >> 6;
    const int lane = tid & 63;
    const int g    = lane >> 4;
    const int lr   = lane & 15;
    const int qrow0 = qt * 64 + wid * 16;
    const int q = qrow0 + lr;

    #define STAGEKV(buf_, kt_) { \
        const u16* Kt_ = Ktl + ((size_t)(b * 32 + (kt_))) * 8192; \
        const u16* Vt_ = Vtl + ((size_t)(b * 32 + (kt_))) * 8192; \
        for (int i_ = 0; i_ < 4; ++i_) \
            gload16(Kt_ + (size_t)(i_ * 256 + tid) * 8, &Ks[buf_][(i_ * 256 + wid * 64) * 8]); \
        for (int i_ = 0; i_ < 4; ++i_) \
            gload16(Vt_ + (size_t)(i_ * 256 + tid) * 8, &Vs[buf_][(i_ * 256 + wid * 64) * 8]); }

    STAGEKV(0, kt0);

    const u16* Qp = Qw + ((size_t)(b * TDIM + qrow0)) * DDIM;
    bf16x8 qf[4];
    for (int kk = 0; kk < 4; ++kk)
        qf[kk] = __builtin_bit_cast(bf16x8, *reinterpret_cast<const u16x8*>(
            &Qp[lr * DDIM + kk * 32 + g * 8]));

    asm volatile("s_waitcnt vmcnt(0)" ::: "memory");
    SCHED_FENCE(); BARRIER(); SCHED_FENCE();

    f32x4 o[8] = {};
    float mrow = -1e30f;
    float lsum = 0.f;
    u32* Pw = &Plw[wid][0];
    int cur = 0;

    for (int kt = kt0; kt < kt1; ++kt) {
        const bool hasnext = (kt + 1 < kt1);
        if (hasnext) STAGEKV(cur ^ 1, kt + 1);

        // S^T = K Q^T
        f32x4 sf[4] = {};
        for (int js = 0; js < 4; ++js)
            for (int kk = 0; kk < 4; ++kk) {
                bf16x8 kf = __builtin_bit_cast(bf16x8, *reinterpret_cast<const u16x8*>(
                    &Ks[cur][kk * 2048 + g * 512 + (js * 16 + lr) * 8]));
                sf[js] = __builtin_amdgcn_mfma_f32_16x16x32_bf16(
                    kf, qf[kk], sf[js], 0, 0, 0);
            }

        // online softmax, per-lane scalar m/l (q-row = lr), defer-max
        float pv[4][4];
        float tmax = -1e30f;
        const bool maskt = (kt == qt);
        const int kvb = kt * 64 + g * 4;
        for (int js = 0; js < 4; ++js)
            for (int r = 0; r < 4; ++r) {
                float v = sf[js][r];
                if (maskt && (kvb + js * 16 + r) > q) v = -1e30f;
                pv[js][r] = v;
                tmax = fmaxf(tmax, v);
            }
        tmax = fmaxf(tmax, __shfl_xor(tmax, 16));
        tmax = fmaxf(tmax, __shfl_xor(tmax, 32));
        const bool rescale = __any(tmax > mrow + 8.0f);
        float al = 1.0f;
        if (rescale) {
            float nm = fmaxf(mrow, tmax);
            al = __expf(mrow - nm);
            mrow = nm;
        }
        float rs = 0.f;
        for (int js = 0; js < 4; ++js)
            for (int r = 0; r < 4; ++r) {
                float p = __expf(pv[js][r] - mrow);
                pv[js][r] = p;
                rs += p;
            }
        rs += __shfl_xor(rs, 16);
        rs += __shfl_xor(rs, 32);
        lsum = lsum * al + rs;

        for (int js = 0; js < 4; ++js) {
            Pw[lr * LDPW + js * 8 + g * 2 + 0] = packbf(pv[js][0], pv[js][1]);
            Pw[lr * LDPW + js * 8 + g * 2 + 1] = packbf(pv[js][2], pv[js][3]);
        }

        if (rescale) {
            float alo[4];
            for (int r = 0; r < 4; ++r)
                alo[r] = __shfl(al, g * 20 + r);
            for (int dt = 0; dt < 8; ++dt)
                for (int r = 0; r < 4; ++r)
                    o[dt][r] *= alo[r];
        }

        // PV
        for (int c = 0; c < 2; ++c) {
            u32x4 prd = *reinterpret_cast<const u32x4*>(&Pw[lr * LDPW + c * 16 + g * 4]);
            bf16x8 pf = __builtin_bit_cast(bf16x8, prd);
            for (int dt = 0; dt < 8; ++dt) {
                bf16x8 vf = __builtin_bit_cast(bf16x8, *reinterpret_cast<const u16x8*>(
                    &Vs[cur][c * 4096 + g * 1024 + (dt * 16 + lr) * 8]));
                o[dt] = __builtin_amdgcn_mfma_f32_16x16x32_bf16(
                    pf, vf, o[dt], 0, 0, 0);
            }
        }

        if (hasnext) {
            asm volatile("s_waitcnt vmcnt(0) lgkmcnt(0)" ::: "memory");
            SCHED_FENCE(); BARRIER(); SCHED_FENCE();
            cur ^= 1;
        }
    }

    float linv = 1.0f / lsum;
    float linvo[4];
    for (int r = 0; r < 4; ++r)
        linvo[r] = __shfl(linv, g * 20 + r);

    if (gg == 0) {
        float* orow = out + ((size_t)(b * TDIM + qrow0)) * DDIM;
        for (int dt = 0; dt < 8; ++dt)
            for (int r = 0; r < 4; ++r)
                orow[(size_t)(g * 4 + r) * DDIM + dt * 16 + lr] = o[dt][r] * linvo[r];
    } else {
        const int slot = (b * 32 + qt) * 8 + split;
        u16* pob = po + (size_t)slot * 8192 + (size_t)(wid * 16) * 128;
        for (int dt = 0; dt < 8; ++dt)
            for (int r = 0; r < 4; ++r)
                pob[(size_t)(g * 4 + r) * 128 + dt * 16 + lr] = f2bf(o[dt][r] * linvo[r]);
        if (g == 0) {
            pm[slot * 64 + wid * 16 + lr] = mrow;
            pl[slot * 64 + wid * 16 + lr] = lsum;
        }
    }
}

// ---------------------------------------------------------------------------
// Kernel 3: combine split-KV partials (qt >= 4).  out = sum_i w_i * O_i
// with w_i = l_i * exp(m_i - M) / L (weights sum to 1; O_i pre-normalized).
// ---------------------------------------------------------------------------
__global__ __launch_bounds__(256) void combine(
    const u16* __restrict__ po, const float* __restrict__ pm,
    const float* __restrict__ pl, float* __restrict__ out)
{
    const int qt = 4 + blockIdx.x;          // 4..31
    const int b  = blockIdx.y;
    const int nsplit = (qt >> 2) + 1;       // 2..8
    const int tid = threadIdx.x;
    const int row = tid >> 2;               // 0..63
    const int cs  = tid & 3;                // 32-col segment
    const int slot0 = (b * 32 + qt) * 8;

    float mv[8], wv[8];
    float M = -1e30f;
    #pragma unroll 8
    for (int i = 0; i < 8; ++i)
        if (i < nsplit) { mv[i] = pm[(slot0 + i) * 64 + row]; M = fmaxf(M, mv[i]); }
    float L = 0.f;
    #pragma unroll 8
    for (int i = 0; i < 8; ++i)
        if (i < nsplit) { wv[i] = pl[(slot0 + i) * 64 + row] * __expf(mv[i] - M); L += wv[i]; }
    float invL = 1.0f / L;

    float acc[32] = {};
    #pragma unroll 8
    for (int i = 0; i < 8; ++i)
        if (i < nsplit) {
            float w = wv[i] * invL;
            const u16* pr = &po[(size_t)(slot0 + i) * 8192 + (size_t)row * 128 + cs * 32];
            for (int j2 = 0; j2 < 4; ++j2) {
                u16x8 v = *reinterpret_cast<const u16x8*>(&pr[j2 * 8]);
                for (int e = 0; e < 8; ++e)
                    acc[j2 * 8 + e] += w * bf2f(v[e]);
            }
        }
    float* orow = &out[((size_t)(b * TDIM) + qt * 64 + row) * DDIM + cs * 32];
    for (int j4 = 0; j4 < 8; ++j4) {
        f32x4 v;
        v[0] = acc[j4*4+0]; v[1] = acc[j4*4+1]; v[2] = acc[j4*4+2]; v[3] = acc[j4*4+3];
        *reinterpret_cast<f32x4*>(&orow[j4 * 4]) = v;
    }
}

extern "C" void kernel_launch(void* const* d_in, const int* in_sizes, int n_in,
                              void* d_out, int out_size, void* d_ws, size_t ws_size,
                              hipStream_t stream) {
    const float* x  = (const float*)d_in[0];
    const float* Wq = (const float*)d_in[1];
    const float* Wk = (const float*)d_in[2];
    const float* Wv = (const float*)d_in[3];
    float* out = (float*)d_out;

    char* base = (char*)d_ws;
    u16*   wb  = (u16*)base;                          // 0.75 MB tiled W
    u16*   Qw  = (u16*)(base + 0x100000);             // 4 MB  [t][128]
    u16*   Ktl = (u16*)(base + 0x500000);             // 4 MB  tiles
    u16*   Vtl = (u16*)(base + 0x900000);             // 4 MB  tiles
    u16*   po  = (u16*)(base + 0xD00000);             // 32 MB bf16 partials
    float* pm  = (float*)(base + 0x2D00000);          // 512 KB
    float* pl  = (float*)(base + 0x2D80000);          // 512 KB

    convert_w<<<dim3(48), dim3(256), 0, stream>>>(Wq, Wk, Wv, wb);
    qkv_gemm<<<dim3(768), dim3(256), 0, stream>>>(x, wb, Qw, Ktl, Vtl);
    attn<<<dim3(144, BATCH), dim3(256), 0, stream>>>(Qw, Ktl, Vtl, out, po, pm, pl);
    combine<<<dim3(28, BATCH), dim3(256), 0, stream>>>(po, pm, pl, out);
}